// Round 1
// baseline (430.631 us; speedup 1.0000x reference)
//
#include <hip/hip_runtime.h>

// Classifier: out[40000][10] = (mean_J relu(x @ Wloc^T)) @ W^T
// x: [1200000][64] f32, Wloc: [128][64] f32, W: [10][128] f32.
// Strategy: bf16 MFMA (16x16x32) for the big matmul; wave owns 16 segments,
// M-tile = one row per segment at offset r, r=0..29; relu+pool in registers.

typedef __bf16 bf16x8 __attribute__((ext_vector_type(8)));
typedef float f32x4 __attribute__((ext_vector_type(4)));

#define NSEG 40000
#define JJ 30
#define DIN 64
#define DENC 128
#define NCLS 10
#define SEG_PER_BLOCK 64   // 4 waves * 16 segments
#define FEATP 130          // padded leading dim: 4*130 % 32 == 8 -> 2-way (free)

union FragU { unsigned u[4]; bf16x8 v; };

// pack two f32 -> one dword of two bf16 (round-to-nearest via +0x8000, then
// v_perm_b32 grabs the high halves). hi lands in bits 31:16, lo in 15:0.
__device__ __forceinline__ unsigned pk_rn(float hi, float lo) {
  unsigned uh = __builtin_bit_cast(unsigned, hi) + 0x8000u;
  unsigned ul = __builtin_bit_cast(unsigned, lo) + 0x8000u;
  return __builtin_amdgcn_perm(uh, ul, 0x07060302u);
}

__global__ __launch_bounds__(256, 2)
void classifier_kernel(const float* __restrict__ x,
                       const float* __restrict__ wloc,
                       const float* __restrict__ w,
                       float* __restrict__ out) {
  __shared__ float s_feats[SEG_PER_BLOCK * FEATP]; // 33,280 B
  __shared__ float s_w[NCLS * DENC];               //  5,120 B

  const int tid  = threadIdx.x;
  const int wid  = tid >> 6;
  const int lane = tid & 63;
  const int quad = lane >> 4;
  const int lrow = lane & 15;

  // stage W into LDS (read after the single __syncthreads below)
  for (int i = tid; i < NCLS * DENC; i += 256) s_w[i] = w[i];

  // B fragments: whole Wloc in registers. B operand holds B^T in A-layout:
  // lane -> (n = lane&15, k = quad*8 + j). B = Wloc^T so B^T = Wloc:
  // element = Wloc[e = nt*16 + lrow][d = ks*32 + quad*8 + j], j consecutive.
  FragU wb[8][2];
#pragma unroll
  for (int nt = 0; nt < 8; ++nt) {
#pragma unroll
    for (int ks = 0; ks < 2; ++ks) {
      const float* p = wloc + (nt * 16 + lrow) * DIN + ks * 32 + quad * 8;
      float4 f0 = *(const float4*)p;
      float4 f1 = *(const float4*)(p + 4);
      wb[nt][ks].u[0] = pk_rn(f0.y, f0.x);
      wb[nt][ks].u[1] = pk_rn(f0.w, f0.z);
      wb[nt][ks].u[2] = pk_rn(f1.y, f1.x);
      wb[nt][ks].u[3] = pk_rn(f1.w, f1.z);
    }
  }

  const int seg0 = blockIdx.x * SEG_PER_BLOCK + wid * 16;
  // A-frag rows: m = lane&15 -> segment seg0+lrow, row offset r, k = quad*8+j
  const float* xbase = x + (size_t)(seg0 + lrow) * JJ * DIN + quad * 8;

  float segsum[8][4];
#pragma unroll
  for (int nt = 0; nt < 8; ++nt)
#pragma unroll
    for (int rg = 0; rg < 4; ++rg) segsum[nt][rg] = 0.f;

#pragma unroll 2
  for (int r = 0; r < JJ; ++r) {
    const float* p = xbase + (size_t)r * DIN;
    float4 v0 = *(const float4*)p;
    float4 v1 = *(const float4*)(p + 4);
    float4 v2 = *(const float4*)(p + 32);
    float4 v3 = *(const float4*)(p + 36);
    FragU a0, a1;
    a0.u[0] = pk_rn(v0.y, v0.x); a0.u[1] = pk_rn(v0.w, v0.z);
    a0.u[2] = pk_rn(v1.y, v1.x); a0.u[3] = pk_rn(v1.w, v1.z);
    a1.u[0] = pk_rn(v2.y, v2.x); a1.u[1] = pk_rn(v2.w, v2.z);
    a1.u[2] = pk_rn(v3.y, v3.x); a1.u[3] = pk_rn(v3.w, v3.z);
#pragma unroll
    for (int nt = 0; nt < 8; ++nt) {
      f32x4 z = {0.f, 0.f, 0.f, 0.f};
      f32x4 acc = __builtin_amdgcn_mfma_f32_16x16x32_bf16(a0.v, wb[nt][0].v, z, 0, 0, 0);
      acc = __builtin_amdgcn_mfma_f32_16x16x32_bf16(a1.v, wb[nt][1].v, acc, 0, 0, 0);
      // relu then pool into fp32 register accumulators.
      // C/D layout: row (=segment idx within wave) = quad*4+rg, col = nt*16 + (lane&15)
#pragma unroll
      for (int rg = 0; rg < 4; ++rg)
        segsum[nt][rg] += fmaxf(acc[rg], 0.f);
    }
  }

  // feats (mean) -> LDS
  const float inv = 1.0f / 30.0f;
#pragma unroll
  for (int nt = 0; nt < 8; ++nt) {
#pragma unroll
    for (int rg = 0; rg < 4; ++rg) {
      int segl = wid * 16 + quad * 4 + rg;
      s_feats[segl * FEATP + nt * 16 + lrow] = segsum[nt][rg] * inv;
    }
  }
  __syncthreads();

  // final tiny matmul: out[seg][c] = dot(feats[seg], W[c]) ; 640 outputs/block
  for (int i = tid; i < SEG_PER_BLOCK * NCLS; i += 256) {
    int sg = i / NCLS;
    int c  = i - sg * NCLS;
    const float* fr = s_feats + sg * FEATP;
    const float* wr = s_w + c * DENC;
    float acc = 0.f;
#pragma unroll 8
    for (int e = 0; e < DENC; ++e) acc += fr[e] * wr[e];
    out[(size_t)(blockIdx.x * SEG_PER_BLOCK + sg) * NCLS + c] = acc;
  }
}

extern "C" void kernel_launch(void* const* d_in, const int* in_sizes, int n_in,
                              void* d_out, int out_size, void* d_ws, size_t ws_size,
                              hipStream_t stream) {
  const float* x    = (const float*)d_in[0];
  const float* wloc = (const float*)d_in[1];
  const float* w    = (const float*)d_in[2];
  float* out = (float*)d_out;
  // 40000 segments / 64 per block = 625 blocks exactly
  classifier_kernel<<<dim3(625), dim3(256), 0, stream>>>(x, wloc, w, out);
}